// Round 1
// baseline (520.890 us; speedup 1.0000x reference)
//
#include <hip/hip_runtime.h>

#define N_NODES 100000
#define N_EDGES 3200000
#define N_CLASSES 16

// Pass 1: degree[row[e]] += w[e]
__global__ void lap_degree_kernel(const int* __restrict__ rows,
                                  const float* __restrict__ w,
                                  float* __restrict__ degree) {
    int i = blockIdx.x * blockDim.x + threadIdx.x;
    if (i < N_EDGES) {
        atomicAdd(&degree[rows[i]], w[i]);
    }
}

// Pass 2: invd[n] = rsqrt(degree[n])
__global__ void lap_invd_kernel(const float* __restrict__ degree,
                                float* __restrict__ invd) {
    int i = blockIdx.x * blockDim.x + threadIdx.x;
    if (i < N_NODES) {
        invd[i] = rsqrtf(degree[i]);
    }
}

// Pass 3: acc += sum_e w[e] * || y[row]*invd[row] - y[col]*invd[col] ||_2
__global__ void lap_edge_kernel(const int* __restrict__ rows,
                                const int* __restrict__ cols,
                                const float* __restrict__ w,
                                const float* __restrict__ y,
                                const float* __restrict__ invd,
                                float* __restrict__ acc) {
    int i = blockIdx.x * blockDim.x + threadIdx.x;
    float local = 0.0f;
    if (i < N_EDGES) {
        int r = rows[i];
        int c = cols[i];
        float dr = invd[r];
        float dc = invd[c];
        const float4* yr = (const float4*)(y + (size_t)r * N_CLASSES);
        const float4* yc = (const float4*)(y + (size_t)c * N_CLASSES);
        float s = 0.0f;
#pragma unroll
        for (int j = 0; j < N_CLASSES / 4; ++j) {
            float4 a = yr[j];
            float4 b = yc[j];
            float d0 = a.x * dr - b.x * dc;
            float d1 = a.y * dr - b.y * dc;
            float d2 = a.z * dr - b.z * dc;
            float d3 = a.w * dr - b.w * dc;
            s += d0 * d0 + d1 * d1 + d2 * d2 + d3 * d3;
        }
        local = w[i] * sqrtf(s);
    }
    // wave (64-lane) shuffle reduction
#pragma unroll
    for (int off = 32; off > 0; off >>= 1) {
        local += __shfl_down(local, off, 64);
    }
    // block reduction via LDS (256 threads = 4 waves)
    __shared__ float sm[4];
    int lane = threadIdx.x & 63;
    int wid  = threadIdx.x >> 6;
    if (lane == 0) sm[wid] = local;
    __syncthreads();
    if (threadIdx.x == 0) {
        float t = sm[0] + sm[1] + sm[2] + sm[3];
        atomicAdd(acc, t);
    }
}

// Pass 4: out = acc / E
__global__ void lap_final_kernel(const float* __restrict__ acc,
                                 float* __restrict__ out) {
    out[0] = acc[0] * (1.0f / (float)N_EDGES);
}

extern "C" void kernel_launch(void* const* d_in, const int* in_sizes, int n_in,
                              void* d_out, int out_size, void* d_ws, size_t ws_size,
                              hipStream_t stream) {
    const int*   edge_index = (const int*)d_in[0];      // (2, E) flattened: [rows | cols]
    const float* w          = (const float*)d_in[1];    // (E,)
    const float* y          = (const float*)d_in[2];    // (N, C)
    float*       out        = (float*)d_out;

    const int* rows = edge_index;
    const int* cols = edge_index + N_EDGES;

    // workspace layout: [degree: N floats][pad to 64B][acc: 1 float][invd: N floats]
    float* degree = (float*)d_ws;
    float* acc    = degree + N_NODES;          // N_NODES*4 = 400000 B, 16B-aligned
    float* invd   = acc + 16;                  // keep invd away from acc's cache line

    // zero degree + acc region (and a little padding) — graph-capture safe
    hipMemsetAsync(d_ws, 0, (size_t)(N_NODES + 16) * sizeof(float), stream);

    const int B = 256;
    lap_degree_kernel<<<(N_EDGES + B - 1) / B, B, 0, stream>>>(rows, w, degree);
    lap_invd_kernel<<<(N_NODES + B - 1) / B, B, 0, stream>>>(degree, invd);
    lap_edge_kernel<<<(N_EDGES + B - 1) / B, B, 0, stream>>>(rows, cols, w, y, invd, acc);
    lap_final_kernel<<<1, 1, 0, stream>>>(acc, out);
}

// Round 2
// 406.010 us; speedup vs baseline: 1.2829x; 1.2829x over previous
//
#include <hip/hip_runtime.h>

#define N_NODES   100000
#define N_CLASSES 16
#define N_EDGES   3200000

// ---- tuning ----
#define P_SHADOW  8        // degree shadow copies (contention reduction)
#define N_PAD     100416   // padded node stride for shadows (non-pow2 spacing)
#define KD        10       // edges per thread, degree pass (E/KD/256 = 1250 blocks exact)
#define KE        4        // edges per quad, edge pass

// ===================== fast path =====================

// Pass 1: degree scatter with shadow copies + batched coalesced loads.
// threads = E/KD = 320000, grid-strided so every load instr is coalesced.
__global__ void lap_degree_p(const int* __restrict__ rows,
                             const float* __restrict__ w,
                             float* __restrict__ degp) {
    const int tid = blockIdx.x * blockDim.x + threadIdx.x;   // 0..319999
    float* mydeg = degp + (size_t)(blockIdx.x & (P_SHADOW - 1)) * N_PAD;
    int   r[KD];
    float wv[KD];
#pragma unroll
    for (int k = 0; k < KD; ++k) {
        int e = tid + k * (N_EDGES / KD);
        r[k]  = rows[e];
        wv[k] = w[e];
    }
#pragma unroll
    for (int k = 0; k < KD; ++k) {
        atomicAdd(&mydeg[r[k]], wv[k]);
    }
}

// Pass 2: yhat[n] = y[n] * rsqrt(sum_p degp[p][n]); 4 lanes per node.
__global__ void lap_yhat_kernel(const float* __restrict__ degp,
                                const float* __restrict__ y,
                                float* __restrict__ yhat) {
    const int tid = blockIdx.x * blockDim.x + threadIdx.x;
    const int n = tid >> 2;
    const int g = tid & 3;
    if (n >= N_NODES) return;
    float deg = 0.0f;
#pragma unroll
    for (int p = 0; p < P_SHADOW; ++p) deg += degp[(size_t)p * N_PAD + n];
    const float inv = rsqrtf(deg);
    float4 v = *(const float4*)(y + (size_t)n * N_CLASSES + g * 4);
    v.x *= inv; v.y *= inv; v.z *= inv; v.w *= inv;
    *(float4*)(yhat + (size_t)n * N_CLASSES + g * 4) = v;
}

// Pass 3: quad-per-edge gather; each quad handles KE consecutive edges.
// threads = 4*E/KE = 3.2M -> 12500 blocks of 256 (exact).
__global__ void lap_edge_quad(const int* __restrict__ rows,
                              const int* __restrict__ cols,
                              const float* __restrict__ w,
                              const float* __restrict__ yhat,
                              float* __restrict__ acc) {
    const int tid = blockIdx.x * blockDim.x + threadIdx.x;
    const int g  = tid & 3;        // lane within quad
    const int e0 = (tid >> 2) * KE;

    int   r[KE], c[KE];
    float wv[KE];
#pragma unroll
    for (int k = 0; k < KE; ++k) {
        r[k]  = rows[e0 + k];
        c[k]  = cols[e0 + k];
        wv[k] = w[e0 + k];
    }
    float4 a[KE], b[KE];
#pragma unroll
    for (int k = 0; k < KE; ++k) {
        a[k] = *(const float4*)(yhat + (size_t)r[k] * N_CLASSES + g * 4);
        b[k] = *(const float4*)(yhat + (size_t)c[k] * N_CLASSES + g * 4);
    }
    float local = 0.0f;
#pragma unroll
    for (int k = 0; k < KE; ++k) {
        float dx = a[k].x - b[k].x;
        float dy = a[k].y - b[k].y;
        float dz = a[k].z - b[k].z;
        float dq = a[k].w - b[k].w;
        float s = dx * dx + dy * dy + dz * dz + dq * dq;
        s += __shfl_xor(s, 1, 64);
        s += __shfl_xor(s, 2, 64);
        if (g == 0) local += wv[k] * sqrtf(s);
    }
    // wave reduce (64 lanes)
#pragma unroll
    for (int off = 32; off > 0; off >>= 1) local += __shfl_down(local, off, 64);
    __shared__ float sm[4];
    const int lane = threadIdx.x & 63;
    const int wid  = threadIdx.x >> 6;
    if (lane == 0) sm[wid] = local;
    __syncthreads();
    if (threadIdx.x == 0) atomicAdd(acc, sm[0] + sm[1] + sm[2] + sm[3]);
}

__global__ void lap_final_kernel(const float* __restrict__ acc,
                                 float* __restrict__ out) {
    out[0] = acc[0] * (1.0f / (float)N_EDGES);
}

// ===================== fallback path (R0, ~800 KB ws) =====================

__global__ void lap_degree_kernel(const int* __restrict__ rows,
                                  const float* __restrict__ w,
                                  float* __restrict__ degree) {
    int i = blockIdx.x * blockDim.x + threadIdx.x;
    if (i < N_EDGES) atomicAdd(&degree[rows[i]], w[i]);
}

__global__ void lap_invd_kernel(const float* __restrict__ degree,
                                float* __restrict__ invd) {
    int i = blockIdx.x * blockDim.x + threadIdx.x;
    if (i < N_NODES) invd[i] = rsqrtf(degree[i]);
}

__global__ void lap_edge_kernel(const int* __restrict__ rows,
                                const int* __restrict__ cols,
                                const float* __restrict__ w,
                                const float* __restrict__ y,
                                const float* __restrict__ invd,
                                float* __restrict__ acc) {
    int i = blockIdx.x * blockDim.x + threadIdx.x;
    float local = 0.0f;
    if (i < N_EDGES) {
        int r = rows[i], c = cols[i];
        float dr = invd[r], dc = invd[c];
        const float4* yr = (const float4*)(y + (size_t)r * N_CLASSES);
        const float4* yc = (const float4*)(y + (size_t)c * N_CLASSES);
        float s = 0.0f;
#pragma unroll
        for (int j = 0; j < N_CLASSES / 4; ++j) {
            float4 a = yr[j], b = yc[j];
            float d0 = a.x * dr - b.x * dc;
            float d1 = a.y * dr - b.y * dc;
            float d2 = a.z * dr - b.z * dc;
            float d3 = a.w * dr - b.w * dc;
            s += d0 * d0 + d1 * d1 + d2 * d2 + d3 * d3;
        }
        local = w[i] * sqrtf(s);
    }
#pragma unroll
    for (int off = 32; off > 0; off >>= 1) local += __shfl_down(local, off, 64);
    __shared__ float sm[4];
    int lane = threadIdx.x & 63, wid = threadIdx.x >> 6;
    if (lane == 0) sm[wid] = local;
    __syncthreads();
    if (threadIdx.x == 0) atomicAdd(acc, sm[0] + sm[1] + sm[2] + sm[3]);
}

// ===================== launch =====================

extern "C" void kernel_launch(void* const* d_in, const int* in_sizes, int n_in,
                              void* d_out, int out_size, void* d_ws, size_t ws_size,
                              hipStream_t stream) {
    const int*   edge_index = (const int*)d_in[0];   // [rows | cols]
    const float* w          = (const float*)d_in[1];
    const float* y          = (const float*)d_in[2];
    float*       out        = (float*)d_out;

    const int* rows = edge_index;
    const int* cols = edge_index + N_EDGES;

    // fast-path workspace layout:
    //   [acc: 64 floats][degp: P_SHADOW*N_PAD floats][yhat: N*C floats]
    const size_t degp_off  = 64;                               // floats
    const size_t yhat_off  = degp_off + (size_t)P_SHADOW * N_PAD;
    const size_t need_fast = (yhat_off + (size_t)N_NODES * N_CLASSES) * sizeof(float);

    const int B = 256;

    if (ws_size >= need_fast) {
        float* acc  = (float*)d_ws;
        float* degp = acc + degp_off;
        float* yhat = acc + yhat_off;

        // zero acc + shadows
        hipMemsetAsync(d_ws, 0, yhat_off * sizeof(float), stream);

        lap_degree_p<<<(N_EDGES / KD) / B, B, 0, stream>>>(rows, w, degp);
        lap_yhat_kernel<<<(4 * N_NODES + B - 1) / B, B, 0, stream>>>(degp, y, yhat);
        lap_edge_quad<<<(4 * N_EDGES / KE) / B, B, 0, stream>>>(rows, cols, w, yhat, acc);
        lap_final_kernel<<<1, 1, 0, stream>>>(acc, out);
    } else {
        // fallback: R0 layout
        float* degree = (float*)d_ws;
        float* acc    = degree + N_NODES;
        float* invd   = acc + 16;
        hipMemsetAsync(d_ws, 0, (size_t)(N_NODES + 16) * sizeof(float), stream);
        lap_degree_kernel<<<(N_EDGES + B - 1) / B, B, 0, stream>>>(rows, w, degree);
        lap_invd_kernel<<<(N_NODES + B - 1) / B, B, 0, stream>>>(degree, invd);
        lap_edge_kernel<<<(N_EDGES + B - 1) / B, B, 0, stream>>>(rows, cols, w, y, invd, acc);
        lap_final_kernel<<<1, 1, 0, stream>>>(acc, out);
    }
}

// Round 3
// 203.476 us; speedup vs baseline: 2.5600x; 1.9954x over previous
//
#include <hip/hip_runtime.h>

#define N_NODES   100000
#define N_CLASSES 16
#define N_EDGES   3200000

// ---- super-path tuning ----
#define R_RANGES   8                    // node ranges (LDS histograms)
#define NODES_PER_RANGE 12500           // 100000 / 8 -> 50 KB LDS
#define S_SLICES   32                   // edge slices
#define EDGES_PER_SLICE (N_EDGES / S_SLICES)   // 100000
#define B_SUPER    1024

// ---- mid-path tuning ----
#define P_SHADOW  8
#define N_PAD     100416
#define KD        10

// ===================== helpers =====================

__device__ __forceinline__ unsigned short f2bf_rne(float f) {
    unsigned u = __float_as_uint(f);
    u += 0x7FFFu + ((u >> 16) & 1u);    // round-to-nearest-even
    return (unsigned short)(u >> 16);
}

// ===================== super path =====================

// Degree: LDS-privatized histogram per (range, slice) block. No global atomics.
__global__ __launch_bounds__(B_SUPER) void lap_degree_super(
        const int* __restrict__ rows, const float* __restrict__ w,
        float* __restrict__ shadows) {
    __shared__ float hist[NODES_PER_RANGE];
    const int r  = blockIdx.x & (R_RANGES - 1);
    const int s  = blockIdx.x >> 3;
    const int lo = r * NODES_PER_RANGE;

    for (int i = threadIdx.x; i < NODES_PER_RANGE; i += B_SUPER) hist[i] = 0.0f;
    __syncthreads();

    const int base = s * EDGES_PER_SLICE;
    // 25000 groups of 4 edges, coalesced int4/float4
    for (int g = threadIdx.x; g < EDGES_PER_SLICE / 4; g += B_SUPER) {
        const int e = base + g * 4;
        int4   r4 = *(const int4*)(rows + e);
        float4 w4 = *(const float4*)(w + e);
        int t;
        t = r4.x - lo; if ((unsigned)t < (unsigned)NODES_PER_RANGE) atomicAdd(&hist[t], w4.x);
        t = r4.y - lo; if ((unsigned)t < (unsigned)NODES_PER_RANGE) atomicAdd(&hist[t], w4.y);
        t = r4.z - lo; if ((unsigned)t < (unsigned)NODES_PER_RANGE) atomicAdd(&hist[t], w4.z);
        t = r4.w - lo; if ((unsigned)t < (unsigned)NODES_PER_RANGE) atomicAdd(&hist[t], w4.w);
    }
    __syncthreads();

    float* dst = shadows + (size_t)s * N_NODES + lo;
    for (int i = threadIdx.x; i < NODES_PER_RANGE; i += B_SUPER) dst[i] = hist[i];
}

// Reduce shadows -> deg -> rsqrt -> yhat(bf16). One thread per node.
__global__ void lap_invd_yhat_super(const float* __restrict__ shadows,
                                    const float* __restrict__ y,
                                    unsigned short* __restrict__ yhat) {
    const int n = blockIdx.x * blockDim.x + threadIdx.x;
    if (n >= N_NODES) return;
    float deg = 0.0f;
#pragma unroll
    for (int s = 0; s < S_SLICES; ++s) deg += shadows[(size_t)s * N_NODES + n];
    const float inv = rsqrtf(deg);

    const float4* yr = (const float4*)(y + (size_t)n * N_CLASSES);
    uint4 o0, o1;
    {
        float4 v0 = yr[0], v1 = yr[1], v2 = yr[2], v3 = yr[3];
        o0.x = f2bf_rne(v0.x * inv) | ((unsigned)f2bf_rne(v0.y * inv) << 16);
        o0.y = f2bf_rne(v0.z * inv) | ((unsigned)f2bf_rne(v0.w * inv) << 16);
        o0.z = f2bf_rne(v1.x * inv) | ((unsigned)f2bf_rne(v1.y * inv) << 16);
        o0.w = f2bf_rne(v1.z * inv) | ((unsigned)f2bf_rne(v1.w * inv) << 16);
        o1.x = f2bf_rne(v2.x * inv) | ((unsigned)f2bf_rne(v2.y * inv) << 16);
        o1.y = f2bf_rne(v2.z * inv) | ((unsigned)f2bf_rne(v2.w * inv) << 16);
        o1.z = f2bf_rne(v3.x * inv) | ((unsigned)f2bf_rne(v3.y * inv) << 16);
        o1.w = f2bf_rne(v3.z * inv) | ((unsigned)f2bf_rne(v3.w * inv) << 16);
    }
    uint4* dst = (uint4*)(yhat + (size_t)n * N_CLASSES);
    dst[0] = o0;
    dst[1] = o1;
}

// ===================== mid path degree (fp32 shadows, global atomics) =====================

__global__ void lap_degree_p(const int* __restrict__ rows,
                             const float* __restrict__ w,
                             float* __restrict__ degp) {
    const int tid = blockIdx.x * blockDim.x + threadIdx.x;
    float* mydeg = degp + (size_t)(blockIdx.x & (P_SHADOW - 1)) * N_PAD;
    int   r[KD];
    float wv[KD];
#pragma unroll
    for (int k = 0; k < KD; ++k) {
        int e = tid + k * (N_EDGES / KD);
        r[k]  = rows[e];
        wv[k] = w[e];
    }
#pragma unroll
    for (int k = 0; k < KD; ++k) atomicAdd(&mydeg[r[k]], wv[k]);
}

__global__ void lap_invd_yhat_mid(const float* __restrict__ degp,
                                  const float* __restrict__ y,
                                  unsigned short* __restrict__ yhat) {
    const int n = blockIdx.x * blockDim.x + threadIdx.x;
    if (n >= N_NODES) return;
    float deg = 0.0f;
#pragma unroll
    for (int p = 0; p < P_SHADOW; ++p) deg += degp[(size_t)p * N_PAD + n];
    const float inv = rsqrtf(deg);
    const float4* yr = (const float4*)(y + (size_t)n * N_CLASSES);
    uint4 o0, o1;
    float4 v0 = yr[0], v1 = yr[1], v2 = yr[2], v3 = yr[3];
    o0.x = f2bf_rne(v0.x * inv) | ((unsigned)f2bf_rne(v0.y * inv) << 16);
    o0.y = f2bf_rne(v0.z * inv) | ((unsigned)f2bf_rne(v0.w * inv) << 16);
    o0.z = f2bf_rne(v1.x * inv) | ((unsigned)f2bf_rne(v1.y * inv) << 16);
    o0.w = f2bf_rne(v1.z * inv) | ((unsigned)f2bf_rne(v1.w * inv) << 16);
    o1.x = f2bf_rne(v2.x * inv) | ((unsigned)f2bf_rne(v2.y * inv) << 16);
    o1.y = f2bf_rne(v2.z * inv) | ((unsigned)f2bf_rne(v2.w * inv) << 16);
    o1.z = f2bf_rne(v3.x * inv) | ((unsigned)f2bf_rne(v3.y * inv) << 16);
    o1.w = f2bf_rne(v3.z * inv) | ((unsigned)f2bf_rne(v3.w * inv) << 16);
    uint4* dst = (uint4*)(yhat + (size_t)n * N_CLASSES);
    dst[0] = o0;
    dst[1] = o1;
}

// ===================== shared edge pass (bf16 pair-per-edge) =====================

// 2 lanes per edge, 4 edges per thread. threads = 2*E/4 = 1.6M -> 6250 blocks.
__global__ void lap_edge_pair(const int* __restrict__ rows,
                              const int* __restrict__ cols,
                              const float* __restrict__ w,
                              const unsigned short* __restrict__ yhat,
                              float* __restrict__ acc) {
    const int tid = blockIdx.x * blockDim.x + threadIdx.x;
    const int g  = tid & 1;              // half (8 classes each)
    const int e0 = (tid >> 1) * 4;

    int4   r4 = *(const int4*)(rows + e0);
    int4   c4 = *(const int4*)(cols + e0);
    float4 w4 = *(const float4*)(w + e0);

    const int goff = g * 8;              // ushort offset within row
    uint4 A[4], B[4];
    A[0] = *(const uint4*)(yhat + (size_t)r4.x * N_CLASSES + goff);
    A[1] = *(const uint4*)(yhat + (size_t)r4.y * N_CLASSES + goff);
    A[2] = *(const uint4*)(yhat + (size_t)r4.z * N_CLASSES + goff);
    A[3] = *(const uint4*)(yhat + (size_t)r4.w * N_CLASSES + goff);
    B[0] = *(const uint4*)(yhat + (size_t)c4.x * N_CLASSES + goff);
    B[1] = *(const uint4*)(yhat + (size_t)c4.y * N_CLASSES + goff);
    B[2] = *(const uint4*)(yhat + (size_t)c4.z * N_CLASSES + goff);
    B[3] = *(const uint4*)(yhat + (size_t)c4.w * N_CLASSES + goff);

    const float wv[4] = {w4.x, w4.y, w4.z, w4.w};
    float local = 0.0f;
#pragma unroll
    for (int k = 0; k < 4; ++k) {
        const unsigned* au = (const unsigned*)&A[k];
        const unsigned* bu = (const unsigned*)&B[k];
        float s = 0.0f;
#pragma unroll
        for (int j = 0; j < 4; ++j) {
            float a_lo = __uint_as_float(au[j] << 16);
            float a_hi = __uint_as_float(au[j] & 0xFFFF0000u);
            float b_lo = __uint_as_float(bu[j] << 16);
            float b_hi = __uint_as_float(bu[j] & 0xFFFF0000u);
            float d0 = a_lo - b_lo;
            float d1 = a_hi - b_hi;
            s += d0 * d0 + d1 * d1;
        }
        s += __shfl_xor(s, 1, 64);       // combine the two halves
        if (g == 0) local += wv[k] * sqrtf(s);
    }
    // wave reduce (g==0 lanes hold values, others 0)
#pragma unroll
    for (int off = 32; off > 0; off >>= 1) local += __shfl_down(local, off, 64);
    __shared__ float sm[4];
    const int lane = threadIdx.x & 63;
    const int wid  = threadIdx.x >> 6;
    if (lane == 0) sm[wid] = local;
    __syncthreads();
    if (threadIdx.x == 0) atomicAdd(acc, sm[0] + sm[1] + sm[2] + sm[3]);
}

__global__ void lap_final_kernel(const float* __restrict__ acc,
                                 float* __restrict__ out) {
    out[0] = acc[0] * (1.0f / (float)N_EDGES);
}

// ===================== low fallback (R0) =====================

__global__ void lap_degree_kernel(const int* __restrict__ rows,
                                  const float* __restrict__ w,
                                  float* __restrict__ degree) {
    int i = blockIdx.x * blockDim.x + threadIdx.x;
    if (i < N_EDGES) atomicAdd(&degree[rows[i]], w[i]);
}

__global__ void lap_invd_kernel(const float* __restrict__ degree,
                                float* __restrict__ invd) {
    int i = blockIdx.x * blockDim.x + threadIdx.x;
    if (i < N_NODES) invd[i] = rsqrtf(degree[i]);
}

__global__ void lap_edge_kernel(const int* __restrict__ rows,
                                const int* __restrict__ cols,
                                const float* __restrict__ w,
                                const float* __restrict__ y,
                                const float* __restrict__ invd,
                                float* __restrict__ acc) {
    int i = blockIdx.x * blockDim.x + threadIdx.x;
    float local = 0.0f;
    if (i < N_EDGES) {
        int r = rows[i], c = cols[i];
        float dr = invd[r], dc = invd[c];
        const float4* yr = (const float4*)(y + (size_t)r * N_CLASSES);
        const float4* yc = (const float4*)(y + (size_t)c * N_CLASSES);
        float s = 0.0f;
#pragma unroll
        for (int j = 0; j < N_CLASSES / 4; ++j) {
            float4 a = yr[j], b = yc[j];
            float d0 = a.x * dr - b.x * dc;
            float d1 = a.y * dr - b.y * dc;
            float d2 = a.z * dr - b.z * dc;
            float d3 = a.w * dr - b.w * dc;
            s += d0 * d0 + d1 * d1 + d2 * d2 + d3 * d3;
        }
        local = w[i] * sqrtf(s);
    }
#pragma unroll
    for (int off = 32; off > 0; off >>= 1) local += __shfl_down(local, off, 64);
    __shared__ float sm[4];
    int lane = threadIdx.x & 63, wid = threadIdx.x >> 6;
    if (lane == 0) sm[wid] = local;
    __syncthreads();
    if (threadIdx.x == 0) atomicAdd(acc, sm[0] + sm[1] + sm[2] + sm[3]);
}

// ===================== launch =====================

extern "C" void kernel_launch(void* const* d_in, const int* in_sizes, int n_in,
                              void* d_out, int out_size, void* d_ws, size_t ws_size,
                              hipStream_t stream) {
    const int*   edge_index = (const int*)d_in[0];   // [rows | cols]
    const float* w          = (const float*)d_in[1];
    const float* y          = (const float*)d_in[2];
    float*       out        = (float*)d_out;

    const int* rows = edge_index;
    const int* cols = edge_index + N_EDGES;
    const int  B = 256;

    // super layout: [acc: 64 f][shadows: 32*N floats][yhat: N*16 bf16]
    const size_t sh_off_f   = 64;
    const size_t yhat_off_b = (sh_off_f + (size_t)S_SLICES * N_NODES) * sizeof(float);
    const size_t need_super = yhat_off_b + (size_t)N_NODES * N_CLASSES * sizeof(unsigned short);

    // mid layout: [acc: 64 f][degp: P*N_PAD floats][yhat bf16]
    const size_t degp_off_f   = 64;
    const size_t yhat_mid_off = (degp_off_f + (size_t)P_SHADOW * N_PAD) * sizeof(float);
    const size_t need_mid     = yhat_mid_off + (size_t)N_NODES * N_CLASSES * sizeof(unsigned short);

    if (ws_size >= need_super) {
        float*          acc     = (float*)d_ws;
        float*          shadows = acc + sh_off_f;
        unsigned short* yhat    = (unsigned short*)((char*)d_ws + yhat_off_b);

        hipMemsetAsync(d_ws, 0, 256, stream);   // acc only; shadows fully overwritten
        lap_degree_super<<<R_RANGES * S_SLICES, B_SUPER, 0, stream>>>(rows, w, shadows);
        lap_invd_yhat_super<<<(N_NODES + B - 1) / B, B, 0, stream>>>(shadows, y, yhat);
        lap_edge_pair<<<(2 * N_EDGES / 4) / B, B, 0, stream>>>(rows, cols, w, yhat, acc);
        lap_final_kernel<<<1, 1, 0, stream>>>(acc, out);
    } else if (ws_size >= need_mid) {
        float*          acc  = (float*)d_ws;
        float*          degp = acc + degp_off_f;
        unsigned short* yhat = (unsigned short*)((char*)d_ws + yhat_mid_off);

        hipMemsetAsync(d_ws, 0, yhat_mid_off, stream);
        lap_degree_p<<<(N_EDGES / KD) / B, B, 0, stream>>>(rows, w, degp);
        lap_invd_yhat_mid<<<(N_NODES + B - 1) / B, B, 0, stream>>>(degp, y, yhat);
        lap_edge_pair<<<(2 * N_EDGES / 4) / B, B, 0, stream>>>(rows, cols, w, yhat, acc);
        lap_final_kernel<<<1, 1, 0, stream>>>(acc, out);
    } else {
        float* degree = (float*)d_ws;
        float* acc    = degree + N_NODES;
        float* invd   = acc + 16;
        hipMemsetAsync(d_ws, 0, (size_t)(N_NODES + 16) * sizeof(float), stream);
        lap_degree_kernel<<<(N_EDGES + B - 1) / B, B, 0, stream>>>(rows, w, degree);
        lap_invd_kernel<<<(N_NODES + B - 1) / B, B, 0, stream>>>(degree, invd);
        lap_edge_kernel<<<(N_EDGES + B - 1) / B, B, 0, stream>>>(rows, cols, w, y, invd, acc);
        lap_final_kernel<<<1, 1, 0, stream>>>(acc, out);
    }
}

// Round 4
// 169.545 us; speedup vs baseline: 3.0723x; 1.2001x over previous
//
#include <hip/hip_runtime.h>

#define N_NODES   100000
#define N_CLASSES 16
#define N_EDGES   3200000

// ---- super-path tuning ----
#define R_RANGES        8
#define NODES_PER_RANGE 12500          // 50 KB LDS histogram
#define B_SUPER         1024
#define KE              8              // edges per thread, edge pass

// ---- mid-path tuning ----
#define P_SHADOW  8
#define N_PAD     100416
#define KD        10

// ===================== fp8 e4m3 helpers (manual, OCP e4m3fn) =====================

// encode fp32 -> e4m3 with RNE (integer-domain rounding; exact for denormals)
__device__ __forceinline__ unsigned f2fp8(float f) {
    unsigned u = __float_as_uint(f);
    unsigned s = (u >> 24) & 0x80u;
    float g = fabsf(f) * 0x1p-120f;           // exact pow2 scale
    unsigned gu = __float_as_uint(g);
    gu += 0x7FFFFu + ((gu >> 20) & 1u);       // RNE at bit 20
    unsigned mag = gu >> 20;
    if (mag > 0x7Eu) mag = 0x7Eu;             // clamp to 448, avoid NaN encoding
    return s | mag;
}

// decode one e4m3 byte -> fp32 (exact, incl. denormals)
__device__ __forceinline__ float fp82f(unsigned b) {
    unsigned u = ((b & 0x80u) << 24) | ((b & 0x7Fu) << 20);
    return __uint_as_float(u) * 0x1p120f;
}

// sum of squared diffs of two packed-fp8 dwords (4 values each)
__device__ __forceinline__ float ssd4(unsigned a, unsigned b) {
    float s = 0.0f;
#pragma unroll
    for (int i = 0; i < 4; ++i) {
        float va = fp82f((a >> (8 * i)) & 0xFFu);
        float vb = fp82f((b >> (8 * i)) & 0xFFu);
        float d = va - vb;
        s += d * d;
    }
    return s;
}

// ===================== degree (LDS histogram, no global atomics) =====================

__global__ __launch_bounds__(B_SUPER) void lap_degree_super(
        const int* __restrict__ rows, const float* __restrict__ w,
        float* __restrict__ shadows, int eps /* edges per slice */) {
    __shared__ float hist[NODES_PER_RANGE];
    const int r  = blockIdx.x & (R_RANGES - 1);
    const int s  = blockIdx.x >> 3;
    const int lo = r * NODES_PER_RANGE;

    for (int i = threadIdx.x; i < NODES_PER_RANGE; i += B_SUPER) hist[i] = 0.0f;
    __syncthreads();

    const int base = s * eps;
    const int ng   = eps >> 2;
    for (int g = threadIdx.x; g < ng; g += B_SUPER) {
        const int e = base + g * 4;
        int4   r4 = *(const int4*)(rows + e);
        float4 w4 = *(const float4*)(w + e);
        int t;
        t = r4.x - lo; if ((unsigned)t < (unsigned)NODES_PER_RANGE) atomicAdd(&hist[t], w4.x);
        t = r4.y - lo; if ((unsigned)t < (unsigned)NODES_PER_RANGE) atomicAdd(&hist[t], w4.y);
        t = r4.z - lo; if ((unsigned)t < (unsigned)NODES_PER_RANGE) atomicAdd(&hist[t], w4.z);
        t = r4.w - lo; if ((unsigned)t < (unsigned)NODES_PER_RANGE) atomicAdd(&hist[t], w4.w);
    }
    __syncthreads();

    float* dst = shadows + (size_t)s * N_NODES + lo;
    for (int i = threadIdx.x; i < NODES_PER_RANGE; i += B_SUPER) dst[i] = hist[i];
}

// ===================== reduce shadows -> rsqrt -> fp8 yhat =====================

__global__ void lap_yhat_super(const float* __restrict__ shadows,
                               const float* __restrict__ y,
                               unsigned char* __restrict__ yhat, int S) {
    const int n = blockIdx.x * blockDim.x + threadIdx.x;
    if (n >= N_NODES) return;
    float deg = 0.0f;
    for (int s = 0; s < S; ++s) deg += shadows[(size_t)s * N_NODES + n];
    const float inv = rsqrtf(deg);

    const float4* yr = (const float4*)(y + (size_t)n * N_CLASSES);
    uint4 o;
    unsigned* op = (unsigned*)&o;
#pragma unroll
    for (int j = 0; j < 4; ++j) {
        float4 v = yr[j];
        op[j] =  f2fp8(v.x * inv)
              | (f2fp8(v.y * inv) << 8)
              | (f2fp8(v.z * inv) << 16)
              | (f2fp8(v.w * inv) << 24);
    }
    *(uint4*)(yhat + (size_t)n * N_CLASSES) = o;
}

// ===================== mid path degree (fp32 shadows, global atomics) =====================

__global__ void lap_degree_p(const int* __restrict__ rows,
                             const float* __restrict__ w,
                             float* __restrict__ degp) {
    const int tid = blockIdx.x * blockDim.x + threadIdx.x;
    float* mydeg = degp + (size_t)(blockIdx.x & (P_SHADOW - 1)) * N_PAD;
    int   r[KD];
    float wv[KD];
#pragma unroll
    for (int k = 0; k < KD; ++k) {
        int e = tid + k * (N_EDGES / KD);
        r[k]  = rows[e];
        wv[k] = w[e];
    }
#pragma unroll
    for (int k = 0; k < KD; ++k) atomicAdd(&mydeg[r[k]], wv[k]);
}

__global__ void lap_yhat_mid(const float* __restrict__ degp,
                             const float* __restrict__ y,
                             unsigned char* __restrict__ yhat) {
    const int n = blockIdx.x * blockDim.x + threadIdx.x;
    if (n >= N_NODES) return;
    float deg = 0.0f;
#pragma unroll
    for (int p = 0; p < P_SHADOW; ++p) deg += degp[(size_t)p * N_PAD + n];
    const float inv = rsqrtf(deg);
    const float4* yr = (const float4*)(y + (size_t)n * N_CLASSES);
    uint4 o;
    unsigned* op = (unsigned*)&o;
#pragma unroll
    for (int j = 0; j < 4; ++j) {
        float4 v = yr[j];
        op[j] =  f2fp8(v.x * inv)
              | (f2fp8(v.y * inv) << 8)
              | (f2fp8(v.z * inv) << 16)
              | (f2fp8(v.w * inv) << 24);
    }
    *(uint4*)(yhat + (size_t)n * N_CLASSES) = o;
}

// ===================== edge pass: fp8, 1 lane/edge, KE edges/thread =====================

__global__ void lap_edge_fp8(const int* __restrict__ rows,
                             const int* __restrict__ cols,
                             const float* __restrict__ w,
                             const unsigned char* __restrict__ yhat,
                             float* __restrict__ acc) {
    const int tid = blockIdx.x * blockDim.x + threadIdx.x;
    const long e0 = (long)tid * KE;
    float local = 0.0f;
    if (e0 < N_EDGES) {
        int4   ra = *(const int4*)(rows + e0);
        int4   rb = *(const int4*)(rows + e0 + 4);
        int4   ca = *(const int4*)(cols + e0);
        int4   cb = *(const int4*)(cols + e0 + 4);
        float4 wa = *(const float4*)(w + e0);
        float4 wb = *(const float4*)(w + e0 + 4);

        const int ri[KE] = {ra.x, ra.y, ra.z, ra.w, rb.x, rb.y, rb.z, rb.w};
        const int ci[KE] = {ca.x, ca.y, ca.z, ca.w, cb.x, cb.y, cb.z, cb.w};
        const float wv[KE] = {wa.x, wa.y, wa.z, wa.w, wb.x, wb.y, wb.z, wb.w};

        uint4 A[KE], B[KE];
#pragma unroll
        for (int k = 0; k < KE; ++k) {
            A[k] = *(const uint4*)(yhat + (size_t)ri[k] * N_CLASSES);
            B[k] = *(const uint4*)(yhat + (size_t)ci[k] * N_CLASSES);
        }
#pragma unroll
        for (int k = 0; k < KE; ++k) {
            float s = ssd4(A[k].x, B[k].x) + ssd4(A[k].y, B[k].y)
                    + ssd4(A[k].z, B[k].z) + ssd4(A[k].w, B[k].w);
            local += wv[k] * sqrtf(s);
        }
    }
#pragma unroll
    for (int off = 32; off > 0; off >>= 1) local += __shfl_down(local, off, 64);
    __shared__ float sm[4];
    const int lane = threadIdx.x & 63;
    const int wid  = threadIdx.x >> 6;
    if (lane == 0) sm[wid] = local;
    __syncthreads();
    if (threadIdx.x == 0) atomicAdd(acc, sm[0] + sm[1] + sm[2] + sm[3]);
}

__global__ void lap_final_kernel(const float* __restrict__ acc,
                                 float* __restrict__ out) {
    out[0] = acc[0] * (1.0f / (float)N_EDGES);
}

// ===================== low fallback (R0) =====================

__global__ void lap_degree_kernel(const int* __restrict__ rows,
                                  const float* __restrict__ w,
                                  float* __restrict__ degree) {
    int i = blockIdx.x * blockDim.x + threadIdx.x;
    if (i < N_EDGES) atomicAdd(&degree[rows[i]], w[i]);
}

__global__ void lap_invd_kernel(const float* __restrict__ degree,
                                float* __restrict__ invd) {
    int i = blockIdx.x * blockDim.x + threadIdx.x;
    if (i < N_NODES) invd[i] = rsqrtf(degree[i]);
}

__global__ void lap_edge_kernel(const int* __restrict__ rows,
                                const int* __restrict__ cols,
                                const float* __restrict__ w,
                                const float* __restrict__ y,
                                const float* __restrict__ invd,
                                float* __restrict__ acc) {
    int i = blockIdx.x * blockDim.x + threadIdx.x;
    float local = 0.0f;
    if (i < N_EDGES) {
        int r = rows[i], c = cols[i];
        float dr = invd[r], dc = invd[c];
        const float4* yr = (const float4*)(y + (size_t)r * N_CLASSES);
        const float4* yc = (const float4*)(y + (size_t)c * N_CLASSES);
        float s = 0.0f;
#pragma unroll
        for (int j = 0; j < N_CLASSES / 4; ++j) {
            float4 a = yr[j], b = yc[j];
            float d0 = a.x * dr - b.x * dc;
            float d1 = a.y * dr - b.y * dc;
            float d2 = a.z * dr - b.z * dc;
            float d3 = a.w * dr - b.w * dc;
            s += d0 * d0 + d1 * d1 + d2 * d2 + d3 * d3;
        }
        local = w[i] * sqrtf(s);
    }
#pragma unroll
    for (int off = 32; off > 0; off >>= 1) local += __shfl_down(local, off, 64);
    __shared__ float sm[4];
    int lane = threadIdx.x & 63, wid = threadIdx.x >> 6;
    if (lane == 0) sm[wid] = local;
    __syncthreads();
    if (threadIdx.x == 0) atomicAdd(acc, sm[0] + sm[1] + sm[2] + sm[3]);
}

// ===================== launch =====================

extern "C" void kernel_launch(void* const* d_in, const int* in_sizes, int n_in,
                              void* d_out, int out_size, void* d_ws, size_t ws_size,
                              hipStream_t stream) {
    const int*   edge_index = (const int*)d_in[0];   // [rows | cols]
    const float* w          = (const float*)d_in[1];
    const float* y          = (const float*)d_in[2];
    float*       out        = (float*)d_out;

    const int* rows = edge_index;
    const int* cols = edge_index + N_EDGES;
    const int  B = 256;

    // super layout: [acc: 64 f][shadows: S*N floats][yhat: N*16 fp8 bytes]
    auto need_super = [](int S) -> size_t {
        return (64 + (size_t)S * N_NODES) * sizeof(float)
             + (size_t)N_NODES * N_CLASSES;
    };
    int S = 0;
    if      (ws_size >= need_super(64)) S = 64;
    else if (ws_size >= need_super(32)) S = 32;
    else if (ws_size >= need_super(16)) S = 16;

    // mid layout: [acc: 64 f][degp: P*N_PAD floats][yhat fp8]
    const size_t yhat_mid_off = (64 + (size_t)P_SHADOW * N_PAD) * sizeof(float);
    const size_t need_mid     = yhat_mid_off + (size_t)N_NODES * N_CLASSES;

    const int edge_threads = N_EDGES / KE;                 // 400000
    const int edge_blocks  = (edge_threads + B - 1) / B;   // 1563

    if (S > 0) {
        float*         acc     = (float*)d_ws;
        float*         shadows = acc + 64;
        unsigned char* yhat    = (unsigned char*)d_ws
                               + (64 + (size_t)S * N_NODES) * sizeof(float);

        hipMemsetAsync(d_ws, 0, 256, stream);   // acc only; shadows fully overwritten
        lap_degree_super<<<R_RANGES * S, B_SUPER, 0, stream>>>(rows, w, shadows, N_EDGES / S);
        lap_yhat_super<<<(N_NODES + B - 1) / B, B, 0, stream>>>(shadows, y, yhat, S);
        lap_edge_fp8<<<edge_blocks, B, 0, stream>>>(rows, cols, w, yhat, acc);
        lap_final_kernel<<<1, 1, 0, stream>>>(acc, out);
    } else if (ws_size >= need_mid) {
        float*         acc  = (float*)d_ws;
        float*         degp = acc + 64;
        unsigned char* yhat = (unsigned char*)d_ws + yhat_mid_off;

        hipMemsetAsync(d_ws, 0, yhat_mid_off, stream);
        lap_degree_p<<<(N_EDGES / KD) / B, B, 0, stream>>>(rows, w, degp);
        lap_yhat_mid<<<(N_NODES + B - 1) / B, B, 0, stream>>>(degp, y, yhat);
        lap_edge_fp8<<<edge_blocks, B, 0, stream>>>(rows, cols, w, yhat, acc);
        lap_final_kernel<<<1, 1, 0, stream>>>(acc, out);
    } else {
        float* degree = (float*)d_ws;
        float* acc    = degree + N_NODES;
        float* invd   = acc + 16;
        hipMemsetAsync(d_ws, 0, (size_t)(N_NODES + 16) * sizeof(float), stream);
        lap_degree_kernel<<<(N_EDGES + B - 1) / B, B, 0, stream>>>(rows, w, degree);
        lap_invd_kernel<<<(N_NODES + B - 1) / B, B, 0, stream>>>(degree, invd);
        lap_edge_kernel<<<(N_EDGES + B - 1) / B, B, 0, stream>>>(rows, cols, w, y, invd, acc);
        lap_final_kernel<<<1, 1, 0, stream>>>(acc, out);
    }
}

// Round 5
// 163.962 us; speedup vs baseline: 3.1769x; 1.0340x over previous
//
#include <hip/hip_runtime.h>
#include <hip/hip_fp16.h>

#define N_NODES   100000
#define N_CLASSES 16
#define N_EDGES   3200000

// ---- dynamic-LDS degree (primary) ----
#define R_DYN     3
#define NPR_DYN   33334                 // nodes per range
#define DYN_BYTES (NPR_DYN * 4)         // 133336 B dynamic LDS
#define S_DYN     85                    // slices -> 255 blocks
#define EPS_DYN   37648                 // edges per slice (div by 4, 85*37648 >= E)

// ---- static-LDS degree (fallback) ----
#define R_ST      8
#define NPR_ST    12500                 // 50 KB static
#define S_ST      64
#define EPS_ST    50000

#define B_DEG     1024
#define KE        8                     // edges per thread, edge pass

// ---- mid-path tuning ----
#define P_SHADOW  8
#define N_PAD     100416
#define KD        10

// ===================== fp8 e4m3 helpers =====================

__device__ __forceinline__ unsigned f2fp8(float f) {
    unsigned u = __float_as_uint(f);
    unsigned s = (u >> 24) & 0x80u;
    float g = fabsf(f) * 0x1p-120f;
    unsigned gu = __float_as_uint(g);
    gu += 0x7FFFFu + ((gu >> 20) & 1u);       // RNE at bit 20
    unsigned mag = gu >> 20;
    if (mag > 0x7Eu) mag = 0x7Eu;             // clamp to 448
    return s | mag;
}

__device__ __forceinline__ float fp82f(unsigned b) {
    unsigned u = ((b & 0x80u) << 24) | ((b & 0x7Fu) << 20);
    return __uint_as_float(u) * 0x1p120f;
}

__device__ __forceinline__ float ssd4(unsigned a, unsigned b) {
    float s = 0.0f;
#pragma unroll
    for (int i = 0; i < 4; ++i) {
        float va = fp82f((a >> (8 * i)) & 0xFFu);
        float vb = fp82f((b >> (8 * i)) & 0xFFu);
        float d = va - vb;
        s += d * d;
    }
    return s;
}

// ===================== degree: dynamic-LDS, R=3 ranges =====================

__global__ __launch_bounds__(B_DEG) void lap_degree_dyn(
        const int* __restrict__ rows, const float* __restrict__ w,
        __half* __restrict__ shadows) {
    extern __shared__ float hist[];
    const int r   = blockIdx.x % R_DYN;
    const int s   = blockIdx.x / R_DYN;
    const int lo  = r * NPR_DYN;
    const int hi  = (lo + NPR_DYN < N_NODES) ? lo + NPR_DYN : N_NODES;
    const int cnt = hi - lo;

    for (int i = threadIdx.x; i < cnt; i += B_DEG) hist[i] = 0.0f;
    __syncthreads();

    const int base = s * EPS_DYN;
    for (int g = threadIdx.x; g < EPS_DYN / 4; g += B_DEG) {
        const int e = base + g * 4;
        if (e >= N_EDGES) continue;               // E % 4 == 0, so e<E => e+4<=E
        int4   r4 = *(const int4*)(rows + e);
        float4 w4 = *(const float4*)(w + e);
        int t;
        t = r4.x - lo; if ((unsigned)t < (unsigned)cnt) atomicAdd(&hist[t], w4.x);
        t = r4.y - lo; if ((unsigned)t < (unsigned)cnt) atomicAdd(&hist[t], w4.y);
        t = r4.z - lo; if ((unsigned)t < (unsigned)cnt) atomicAdd(&hist[t], w4.z);
        t = r4.w - lo; if ((unsigned)t < (unsigned)cnt) atomicAdd(&hist[t], w4.w);
    }
    __syncthreads();

    __half* dst = shadows + (size_t)s * N_NODES + lo;
    for (int i = threadIdx.x; i < cnt; i += B_DEG) dst[i] = __float2half(hist[i]);
}

// ===================== degree: static-LDS fallback, R=8 =====================

__global__ __launch_bounds__(B_DEG) void lap_degree_static(
        const int* __restrict__ rows, const float* __restrict__ w,
        __half* __restrict__ shadows) {
    __shared__ float hist[NPR_ST];
    const int r  = blockIdx.x & (R_ST - 1);
    const int s  = blockIdx.x >> 3;
    const int lo = r * NPR_ST;

    for (int i = threadIdx.x; i < NPR_ST; i += B_DEG) hist[i] = 0.0f;
    __syncthreads();

    const int base = s * EPS_ST;
    for (int g = threadIdx.x; g < EPS_ST / 4; g += B_DEG) {
        const int e = base + g * 4;
        int4   r4 = *(const int4*)(rows + e);
        float4 w4 = *(const float4*)(w + e);
        int t;
        t = r4.x - lo; if ((unsigned)t < (unsigned)NPR_ST) atomicAdd(&hist[t], w4.x);
        t = r4.y - lo; if ((unsigned)t < (unsigned)NPR_ST) atomicAdd(&hist[t], w4.y);
        t = r4.z - lo; if ((unsigned)t < (unsigned)NPR_ST) atomicAdd(&hist[t], w4.z);
        t = r4.w - lo; if ((unsigned)t < (unsigned)NPR_ST) atomicAdd(&hist[t], w4.w);
    }
    __syncthreads();

    __half* dst = shadows + (size_t)s * N_NODES + lo;
    for (int i = threadIdx.x; i < NPR_ST; i += B_DEG) dst[i] = __float2half(hist[i]);
}

// ===================== reduce shadows -> rsqrt -> fp8 yhat =====================

__global__ void lap_yhat_super(const __half* __restrict__ shadows,
                               const float* __restrict__ y,
                               unsigned char* __restrict__ yhat, int S) {
    const int n = blockIdx.x * blockDim.x + threadIdx.x;
    if (n >= N_NODES) return;
    float deg = 0.0f;
    for (int s = 0; s < S; ++s) deg += __half2float(shadows[(size_t)s * N_NODES + n]);
    const float inv = rsqrtf(deg);

    const float4* yr = (const float4*)(y + (size_t)n * N_CLASSES);
    uint4 o;
    unsigned* op = (unsigned*)&o;
#pragma unroll
    for (int j = 0; j < 4; ++j) {
        float4 v = yr[j];
        op[j] =  f2fp8(v.x * inv)
              | (f2fp8(v.y * inv) << 8)
              | (f2fp8(v.z * inv) << 16)
              | (f2fp8(v.w * inv) << 24);
    }
    *(uint4*)(yhat + (size_t)n * N_CLASSES) = o;
}

// ===================== mid path degree (fp32 shadows, global atomics) =====================

__global__ void lap_degree_p(const int* __restrict__ rows,
                             const float* __restrict__ w,
                             float* __restrict__ degp) {
    const int tid = blockIdx.x * blockDim.x + threadIdx.x;
    float* mydeg = degp + (size_t)(blockIdx.x & (P_SHADOW - 1)) * N_PAD;
    int   r[KD];
    float wv[KD];
#pragma unroll
    for (int k = 0; k < KD; ++k) {
        int e = tid + k * (N_EDGES / KD);
        r[k]  = rows[e];
        wv[k] = w[e];
    }
#pragma unroll
    for (int k = 0; k < KD; ++k) atomicAdd(&mydeg[r[k]], wv[k]);
}

__global__ void lap_yhat_mid(const float* __restrict__ degp,
                             const float* __restrict__ y,
                             unsigned char* __restrict__ yhat) {
    const int n = blockIdx.x * blockDim.x + threadIdx.x;
    if (n >= N_NODES) return;
    float deg = 0.0f;
#pragma unroll
    for (int p = 0; p < P_SHADOW; ++p) deg += degp[(size_t)p * N_PAD + n];
    const float inv = rsqrtf(deg);
    const float4* yr = (const float4*)(y + (size_t)n * N_CLASSES);
    uint4 o;
    unsigned* op = (unsigned*)&o;
#pragma unroll
    for (int j = 0; j < 4; ++j) {
        float4 v = yr[j];
        op[j] =  f2fp8(v.x * inv)
              | (f2fp8(v.y * inv) << 8)
              | (f2fp8(v.z * inv) << 16)
              | (f2fp8(v.w * inv) << 24);
    }
    *(uint4*)(yhat + (size_t)n * N_CLASSES) = o;
}

// ===================== edge pass: fp8, KE edges/thread, fused mean =====================

__global__ void lap_edge_fp8(const int* __restrict__ rows,
                             const int* __restrict__ cols,
                             const float* __restrict__ w,
                             const unsigned char* __restrict__ yhat,
                             float* __restrict__ out) {
    const int tid = blockIdx.x * blockDim.x + threadIdx.x;
    const long e0 = (long)tid * KE;
    float local = 0.0f;
    if (e0 < N_EDGES) {
        int4   ra = *(const int4*)(rows + e0);
        int4   rb = *(const int4*)(rows + e0 + 4);
        int4   ca = *(const int4*)(cols + e0);
        int4   cb = *(const int4*)(cols + e0 + 4);
        float4 wa = *(const float4*)(w + e0);
        float4 wb = *(const float4*)(w + e0 + 4);

        const int ri[KE] = {ra.x, ra.y, ra.z, ra.w, rb.x, rb.y, rb.z, rb.w};
        const int ci[KE] = {ca.x, ca.y, ca.z, ca.w, cb.x, cb.y, cb.z, cb.w};
        const float wv[KE] = {wa.x, wa.y, wa.z, wa.w, wb.x, wb.y, wb.z, wb.w};

        uint4 A[KE], B[KE];
#pragma unroll
        for (int k = 0; k < KE; ++k) {
            A[k] = *(const uint4*)(yhat + (size_t)ri[k] * N_CLASSES);
            B[k] = *(const uint4*)(yhat + (size_t)ci[k] * N_CLASSES);
        }
#pragma unroll
        for (int k = 0; k < KE; ++k) {
            float s = ssd4(A[k].x, B[k].x) + ssd4(A[k].y, B[k].y)
                    + ssd4(A[k].z, B[k].z) + ssd4(A[k].w, B[k].w);
            local += wv[k] * sqrtf(s);
        }
    }
#pragma unroll
    for (int off = 32; off > 0; off >>= 1) local += __shfl_down(local, off, 64);
    __shared__ float sm[4];
    const int lane = threadIdx.x & 63;
    const int wid  = threadIdx.x >> 6;
    if (lane == 0) sm[wid] = local;
    __syncthreads();
    if (threadIdx.x == 0)
        atomicAdd(out, (sm[0] + sm[1] + sm[2] + sm[3]) * (1.0f / (float)N_EDGES));
}

// ===================== low fallback (R0-style, fused mean) =====================

__global__ void lap_degree_kernel(const int* __restrict__ rows,
                                  const float* __restrict__ w,
                                  float* __restrict__ degree) {
    int i = blockIdx.x * blockDim.x + threadIdx.x;
    if (i < N_EDGES) atomicAdd(&degree[rows[i]], w[i]);
}

__global__ void lap_invd_kernel(const float* __restrict__ degree,
                                float* __restrict__ invd) {
    int i = blockIdx.x * blockDim.x + threadIdx.x;
    if (i < N_NODES) invd[i] = rsqrtf(degree[i]);
}

__global__ void lap_edge_kernel(const int* __restrict__ rows,
                                const int* __restrict__ cols,
                                const float* __restrict__ w,
                                const float* __restrict__ y,
                                const float* __restrict__ invd,
                                float* __restrict__ out) {
    int i = blockIdx.x * blockDim.x + threadIdx.x;
    float local = 0.0f;
    if (i < N_EDGES) {
        int r = rows[i], c = cols[i];
        float dr = invd[r], dc = invd[c];
        const float4* yr = (const float4*)(y + (size_t)r * N_CLASSES);
        const float4* yc = (const float4*)(y + (size_t)c * N_CLASSES);
        float s = 0.0f;
#pragma unroll
        for (int j = 0; j < N_CLASSES / 4; ++j) {
            float4 a = yr[j], b = yc[j];
            float d0 = a.x * dr - b.x * dc;
            float d1 = a.y * dr - b.y * dc;
            float d2 = a.z * dr - b.z * dc;
            float d3 = a.w * dr - b.w * dc;
            s += d0 * d0 + d1 * d1 + d2 * d2 + d3 * d3;
        }
        local = w[i] * sqrtf(s);
    }
#pragma unroll
    for (int off = 32; off > 0; off >>= 1) local += __shfl_down(local, off, 64);
    __shared__ float sm[4];
    int lane = threadIdx.x & 63, wid = threadIdx.x >> 6;
    if (lane == 0) sm[wid] = local;
    __syncthreads();
    if (threadIdx.x == 0)
        atomicAdd(out, (sm[0] + sm[1] + sm[2] + sm[3]) * (1.0f / (float)N_EDGES));
}

// ===================== launch =====================

extern "C" void kernel_launch(void* const* d_in, const int* in_sizes, int n_in,
                              void* d_out, int out_size, void* d_ws, size_t ws_size,
                              hipStream_t stream) {
    const int*   edge_index = (const int*)d_in[0];   // [rows | cols]
    const float* w          = (const float*)d_in[1];
    const float* y          = (const float*)d_in[2];
    float*       out        = (float*)d_out;

    const int* rows = edge_index;
    const int* cols = edge_index + N_EDGES;
    const int  B = 256;

    // super layout: [shadows: max(S)*N halves][yhat: N*16 fp8 bytes]
    const size_t sh_bytes   = (size_t)S_DYN * N_NODES * sizeof(__half);   // 17 MB
    const size_t need_super = sh_bytes + (size_t)N_NODES * N_CLASSES;

    // mid layout: [degp: P*N_PAD floats][yhat fp8]
    const size_t yhat_mid_off = (size_t)P_SHADOW * N_PAD * sizeof(float);
    const size_t need_mid     = yhat_mid_off + (size_t)N_NODES * N_CLASSES;

    const int edge_blocks = (N_EDGES / KE + B - 1) / B;   // 1563

    // out accumulates directly; zero it (harness poisons with 0xAA)
    hipMemsetAsync(d_out, 0, sizeof(float), stream);

    if (ws_size >= need_super) {
        __half*        shadows = (__half*)d_ws;
        unsigned char* yhat    = (unsigned char*)d_ws + sh_bytes;

        hipError_t attr_ok = hipFuncSetAttribute(
            reinterpret_cast<const void*>(lap_degree_dyn),
            hipFuncAttributeMaxDynamicSharedMemorySize, DYN_BYTES);

        if (attr_ok == hipSuccess) {
            lap_degree_dyn<<<R_DYN * S_DYN, B_DEG, DYN_BYTES, stream>>>(rows, w, shadows);
            lap_yhat_super<<<(N_NODES + B - 1) / B, B, 0, stream>>>(shadows, y, yhat, S_DYN);
        } else {
            lap_degree_static<<<R_ST * S_ST, B_DEG, 0, stream>>>(rows, w, shadows);
            lap_yhat_super<<<(N_NODES + B - 1) / B, B, 0, stream>>>(shadows, y, yhat, S_ST);
        }
        lap_edge_fp8<<<edge_blocks, B, 0, stream>>>(rows, cols, w, yhat, out);
    } else if (ws_size >= need_mid) {
        float*         degp = (float*)d_ws;
        unsigned char* yhat = (unsigned char*)d_ws + yhat_mid_off;

        hipMemsetAsync(d_ws, 0, yhat_mid_off, stream);
        lap_degree_p<<<(N_EDGES / KD) / B, B, 0, stream>>>(rows, w, degp);
        lap_yhat_mid<<<(N_NODES + B - 1) / B, B, 0, stream>>>(degp, y, yhat);
        lap_edge_fp8<<<edge_blocks, B, 0, stream>>>(rows, cols, w, yhat, out);
    } else {
        float* degree = (float*)d_ws;
        float* invd   = degree + N_NODES;
        hipMemsetAsync(d_ws, 0, (size_t)N_NODES * sizeof(float), stream);
        lap_degree_kernel<<<(N_EDGES + B - 1) / B, B, 0, stream>>>(rows, w, degree);
        lap_invd_kernel<<<(N_NODES + B - 1) / B, B, 0, stream>>>(degree, invd);
        lap_edge_kernel<<<(N_EDGES + B - 1) / B, B, 0, stream>>>(rows, cols, w, y, invd, out);
    }
}